// Round 20
// baseline (495.442 us; speedup 1.0000x reference)
//
#include <hip/hip_runtime.h>
#include <hip/hip_bf16.h>

typedef __bf16 bf16x8 __attribute__((ext_vector_type(8)));
typedef __bf16 bf16x4 __attribute__((ext_vector_type(4)));
typedef float f32x4 __attribute__((ext_vector_type(4)));

// ---- problem constants: B=4, S=2048, E=1024, H=16, D=64 ----
// ws layout (bf16 element offsets)
constexpr size_t XQ_OFF = 0;                 // x bf16 [8192][1024] x3 ; reused as f32 rowsums after gemm0
constexpr size_t WQ_OFF = 25165824;          // W bf16 [1024][1024] x4
constexpr size_t Q_OFF  = 29360128;          // Q bf16 [bh][s][d]
constexpr size_t KK_OFF = 37748736;          // K bf16 [bh][s][d]
constexpr size_t VT_OFF = 46137344;          // V^T bf16 [bh][d][s]
constexpr size_t CTX_OFF= 54525952;          // ctx merged bf16 [8192][1024]

__device__ __forceinline__ void gload16(const void* g, void* s) {
    __builtin_amdgcn_global_load_lds((__attribute__((address_space(1))) void*)g,
                                     (__attribute__((address_space(3))) void*)s, 16, 0, 0);
}
#define WAIT_VM0()   asm volatile("s_waitcnt vmcnt(0)" ::: "memory")
#define WAIT_VM4()   asm volatile("s_waitcnt vmcnt(4)" ::: "memory")
#define WAIT_VM8()   asm volatile("s_waitcnt vmcnt(8)" ::: "memory")
#define WAIT_LGKM0() asm volatile("s_waitcnt lgkmcnt(0)" ::: "memory")
#define BAR()        __builtin_amdgcn_s_barrier()

// ---------------- convert fp32 -> bf16 into ws ----------------
__global__ __launch_bounds__(256) void convert_k(
    const float* __restrict__ q, const float* __restrict__ k, const float* __restrict__ v,
    const float* __restrict__ Wq, const float* __restrict__ Wk, const float* __restrict__ Wv,
    const float* __restrict__ Wo, __bf16* __restrict__ ws) {
    int id = blockIdx.x * 256 + threadIdx.x;
    const int NX = 1048576;
    const int NW = 131072;
    const float* src; size_t dst; int local;
    if (id < 3 * NX) {
        int z = id / NX; local = id - z * NX;
        src = (z == 0) ? q : ((z == 1) ? k : v);
        dst = XQ_OFF + (size_t)z * 8388608;
    } else {
        int i2 = id - 3 * NX;
        int z = i2 / NW; local = i2 - z * NW;
        src = (z == 0) ? Wq : ((z == 1) ? Wk : ((z == 2) ? Wv : Wo));
        dst = WQ_OFF + (size_t)z * 1048576;
    }
    const float4* s4 = (const float4*)(src + (size_t)local * 8);
    float4 a = s4[0], b = s4[1];
    bf16x8 o;
    o[0]=(__bf16)a.x; o[1]=(__bf16)a.y; o[2]=(__bf16)a.z; o[3]=(__bf16)a.w;
    o[4]=(__bf16)b.x; o[5]=(__bf16)b.y; o[6]=(__bf16)b.z; o[7]=(__bf16)b.w;
    *(bf16x8*)(ws + dst + (size_t)local * 8) = o;
}

// ---------------- GEMM  C = A @ B^T (+bias), 128x128/BK32, 2-phase dbuf ----------------
template<int MODE>
__global__ __launch_bounds__(256) void gemm_k(
    __bf16* __restrict__ ws,
    const float* __restrict__ bq, const float* __restrict__ bk,
    const float* __restrict__ bv, const float* __restrict__ bo,
    float* __restrict__ out) {
    const int K = 1024;
    unsigned n = blockIdx.x + 64u * (blockIdx.y + 8u * blockIdx.z);
    unsigned cpx = (MODE == 0) ? 192u : 64u;
    unsigned m_ = (n & 7u) * cpx + (n >> 3);
    unsigned bx = m_ & 63u;
    unsigned rest = m_ >> 6;
    unsigned by = rest & 7u;
    unsigned bz = rest >> 3;

    int z = (int)bz;
    const __bf16* A; const __bf16* Bm; const float* bias;
    if (MODE == 0) {
        A    = ws + XQ_OFF + (size_t)z * 8388608;
        Bm   = ws + WQ_OFF + (size_t)z * 1048576;
        bias = (z == 0) ? bq : ((z == 1) ? bk : bv);
    } else {
        A    = ws + CTX_OFF;
        Bm   = ws + WQ_OFF + (size_t)3 * 1048576;
        bias = bo;
    }
    int row0 = (int)bx * 128, col0 = (int)by * 128;
    __shared__ __align__(16) __bf16 As[2][128 * 32];
    __shared__ __align__(16) __bf16 Bs[2][128 * 32];
    int t = threadIdx.x, lane = t & 63, w = t >> 6;
    int wr = w >> 1, wc = w & 1;
    f32x4 acc[4][4];
#pragma unroll
    for (int i = 0; i < 4; ++i)
#pragma unroll
        for (int j = 0; j < 4; ++j) acc[i][j] = (f32x4){0.f, 0.f, 0.f, 0.f};

    auto stage = [&](int buf, int kt) {
#pragma unroll
        for (int i = 0; i < 2; ++i) {
            int e = ((i * 4 + w) * 64 + lane) * 8;
            int r = e >> 5, c = e & 31;
            gload16(A  + (size_t)(row0 + r) * K + kt + c, &As[buf][e]);
            gload16(Bm + (size_t)(col0 + r) * K + kt + c, &Bs[buf][e]);
        }
    };

    stage(0, 0);
    int cur = 0;
    for (int kt = 0; kt < K; kt += 32) {
        bool nx = kt + 32 < K;
        if (nx) { stage(cur ^ 1, kt + 32); WAIT_VM4(); }
        else    { WAIT_VM0(); }
        BAR();
        const __bf16* Ac = As[cur];
        const __bf16* Bc = Bs[cur];
        bf16x8 af[4], bfr[4];
#pragma unroll
        for (int f = 0; f < 4; ++f) {
            af[f]  = *(const bf16x8*)&Ac[(wr * 64 + f * 16 + (lane & 15)) * 32 + (lane >> 4) * 8];
            bfr[f] = *(const bf16x8*)&Bc[(wc * 64 + f * 16 + (lane & 15)) * 32 + (lane >> 4) * 8];
        }
#pragma unroll
        for (int fr = 0; fr < 4; ++fr)
#pragma unroll
            for (int fc = 0; fc < 4; ++fc)
                acc[fr][fc] = __builtin_amdgcn_mfma_f32_16x16x32_bf16(af[fr], bfr[fc], acc[fr][fc], 0, 0, 0);
        WAIT_LGKM0();
        BAR();
        cur ^= 1;
    }

    if (MODE == 0) {
        __bf16* dqk = ws + Q_OFF + (size_t)z * 8388608;
        __bf16* dvt = ws + VT_OFF;
#pragma unroll
        for (int fr = 0; fr < 4; ++fr)
#pragma unroll
            for (int fc = 0; fc < 4; ++fc)
#pragma unroll
                for (int r = 0; r < 4; ++r) {
                    int m = row0 + wr * 64 + fr * 16 + ((lane >> 4) << 2) + r;
                    int nn = col0 + wc * 64 + fc * 16 + (lane & 15);
                    float val = acc[fr][fc][r] + bias[nn];
                    int bb = m >> 11, s = m & 2047, h = nn >> 6, d = nn & 63;
                    size_t bh = (size_t)bb * 16 + h;
                    if (z < 2) dqk[bh * 131072 + (size_t)s * 64 + d] = (__bf16)val;
                    else       dvt[bh * 131072 + (size_t)d * 2048 + s] = (__bf16)val;
                }
    } else {
#pragma unroll
        for (int fr = 0; fr < 4; ++fr)
#pragma unroll
            for (int fc = 0; fc < 4; ++fc)
#pragma unroll
                for (int r = 0; r < 4; ++r) {
                    int m = row0 + wr * 64 + fr * 16 + ((lane >> 4) << 2) + r;
                    int nn = col0 + wc * 64 + fc * 16 + (lane & 15);
                    out[(size_t)m * 1024 + nn] = acc[fr][fc][r] + bias[nn];
                }
    }
}

// ---------------- pass 1: rowsums of exp(QK^T/8), QBLK=256, Q in regs ----------------
__global__ __launch_bounds__(512) void rowsum_k(const __bf16* __restrict__ ws,
                                                float* __restrict__ rs_out) {
    unsigned n = blockIdx.x + 8u * blockIdx.y;
    unsigned m = (n & 7u) * 64u + (n >> 3);
    int bh = (int)(m >> 3);
    int q0 = (int)(m & 7u) * 256;
    const __bf16* Qb = ws + Q_OFF  + (size_t)bh * 131072;
    const __bf16* Kb = ws + KK_OFF + (size_t)bh * 131072;
    __shared__ __align__(16) __bf16 Ks[2][64 * 64];
    int t = threadIdx.x, lane = t & 63, w = t >> 6, g = lane >> 4;
    const float SCALE = 0.125f;

    bf16x8 aq[2][2];
#pragma unroll
    for (int f = 0; f < 2; ++f) {
        int qr = q0 + w * 32 + f * 16 + (lane & 15);
        aq[f][0] = *(const bf16x8*)&Qb[(size_t)qr * 64 + g * 8];
        aq[f][1] = *(const bf16x8*)&Qb[(size_t)qr * 64 + 32 + g * 8];
    }

    { int r = t >> 3, c8 = t & 7;
      gload16(Kb + (size_t)r * 64 + ((c8 ^ (r & 7)) << 3), &Ks[0][t * 8]); }
    WAIT_VM0(); BAR();

    float rs[8] = {0.f,0.f,0.f,0.f,0.f,0.f,0.f,0.f};
    int cur = 0;
    for (int kt = 0; kt < 2048; kt += 64) {
        bool nx = kt < 1984;
        if (nx) {
            int r = t >> 3, c8 = t & 7;
            gload16(Kb + (size_t)(kt + 64 + r) * 64 + ((c8 ^ (r & 7)) << 3), &Ks[cur ^ 1][t * 8]);
        }
        const __bf16* Kc = Ks[cur];
        __builtin_amdgcn_s_setprio(1);
#pragma unroll
        for (int kc = 0; kc < 4; ++kc) {
            int krow = kc * 16 + (lane & 15);
            bf16x8 b0 = *(const bf16x8*)((const char*)Kc + krow * 128 + ((g * 16) ^ ((krow & 7) << 4)));
            bf16x8 b1 = *(const bf16x8*)((const char*)Kc + krow * 128 + (((4 + g) * 16) ^ ((krow & 7) << 4)));
#pragma unroll
            for (int f = 0; f < 2; ++f) {
                f32x4 s = (f32x4){0.f, 0.f, 0.f, 0.f};
                s = __builtin_amdgcn_mfma_f32_16x16x32_bf16(aq[f][0], b0, s, 0, 0, 0);
                s = __builtin_amdgcn_mfma_f32_16x16x32_bf16(aq[f][1], b1, s, 0, 0, 0);
#pragma unroll
                for (int r4 = 0; r4 < 4; ++r4) rs[f * 4 + r4] += __expf(s[r4] * SCALE);
            }
        }
        __builtin_amdgcn_s_setprio(0);
        WAIT_LGKM0();
        if (nx) WAIT_VM0();
        BAR();
        cur ^= 1;
    }
#pragma unroll
    for (int msk = 1; msk < 16; msk <<= 1)
#pragma unroll
        for (int i = 0; i < 8; ++i) rs[i] += __shfl_xor(rs[i], msk);
    if ((lane & 15) == 0) {
#pragma unroll
        for (int f = 0; f < 2; ++f)
#pragma unroll
            for (int r4 = 0; r4 < 4; ++r4)
                rs_out[(size_t)bh * 2048 + q0 + w * 32 + f * 16 + g * 4 + r4] = rs[f * 4 + r4];
    }
}

// ---------------- pass 2: swapped QK^T; weights staged f32 in LDS, stored FULL-LINE ----------------
// Per f-half: compute -> Pf LDS (32KB, XOR-swizzled 16B chunks) -> fill-style store where
// lanes 0-15 write 16 consecutive 16B chunks of one row => each 8-lane group = one full 128B line.
__global__ __launch_bounds__(512) void attnw_k(const __bf16* __restrict__ ws,
                                               const float* __restrict__ rsf,
                                               __bf16* __restrict__ wsw,
                                               float* __restrict__ wout) {
    unsigned n = blockIdx.x + 8u * blockIdx.y;
    unsigned m = (n & 7u) * 64u + (n >> 3);
    int bh = (int)(m >> 3);
    int q0 = (int)(m & 7u) * 256;

    const __bf16* Qb = ws + Q_OFF  + (size_t)bh * 131072;
    const __bf16* Kb = ws + KK_OFF + (size_t)bh * 131072;
    const __bf16* Vb = ws + VT_OFF + (size_t)bh * 131072;
    __bf16* ctx = wsw + CTX_OFF;

    int t = threadIdx.x, lane = t & 63, w = t >> 6, g = lane >> 4, q = lane & 15;
    __shared__ __align__(16) __bf16 Ks[2][64 * 64];
    __shared__ __align__(16) __bf16 Vts[2][64 * 64];
    __shared__ __align__(16) float Pf[128 * 64];        // 32KB, one f-half at a time
    const float SCALE = 0.125f;

    bf16x8 aq[2][2];
#pragma unroll
    for (int f = 0; f < 2; ++f) {
        int qr = q0 + w * 32 + f * 16 + q;
        aq[f][0] = *(const bf16x8*)&Qb[(size_t)qr * 64 + g * 8];
        aq[f][1] = *(const bf16x8*)&Qb[(size_t)qr * 64 + 32 + g * 8];
    }
    float rinv[2];
#pragma unroll
    for (int f = 0; f < 2; ++f)
        rinv[f] = 1.f / rsf[(size_t)bh * 2048 + q0 + w * 32 + f * 16 + q];

    { int r = t >> 3, c8 = t & 7;
      gload16(Kb + (size_t)r * 64   + ((c8 ^ (r & 7)) << 3), &Ks[0][t * 8]);
      gload16(Vb + (size_t)r * 2048 + ((c8 ^ (r & 7)) << 3), &Vts[0][t * 8]); }
    WAIT_VM0(); BAR();

    f32x4 cacc[2][4];
#pragma unroll
    for (int f = 0; f < 2; ++f)
#pragma unroll
        for (int dc = 0; dc < 4; ++dc) cacc[f][dc] = (f32x4){0.f, 0.f, 0.f, 0.f};

    int cur = 0;
    for (int kt = 0; kt < 2048; kt += 64) {
        bool nx = kt < 1984;
        if (nx) {
            int r = t >> 3, c8 = t & 7;
            gload16(Kb + (size_t)(kt + 64 + r) * 64 + ((c8 ^ (r & 7)) << 3), &Ks[cur ^ 1][t * 8]);
            gload16(Vb + (size_t)r * 2048 + (kt + 64) + ((c8 ^ (r & 7)) << 3), &Vts[cur ^ 1][t * 8]);
        }
        const __bf16* Kc = Ks[cur];
        const __bf16* Vc = Vts[cur];

        int2 pk[2][4];
#pragma unroll
        for (int f = 0; f < 2; ++f) {
            // ---- QK^T (swapped) -> exp*rinv -> Pf LDS + bf16 pack ----
#pragma unroll
            for (int kc = 0; kc < 4; ++kc) {
                int krow = kc * 16 + q;
                bf16x8 b0 = *(const bf16x8*)((const char*)Kc + krow * 128 + ((g * 16) ^ ((krow & 7) << 4)));
                bf16x8 b1 = *(const bf16x8*)((const char*)Kc + krow * 128 + (((4 + g) * 16) ^ ((krow & 7) << 4)));
                f32x4 s = (f32x4){0.f, 0.f, 0.f, 0.f};
                s = __builtin_amdgcn_mfma_f32_16x16x32_bf16(b0, aq[f][0], s, 0, 0, 0);  // A=K, B=Q
                s = __builtin_amdgcn_mfma_f32_16x16x32_bf16(b1, aq[f][1], s, 0, 0, 0);
                f32x4 e4;
#pragma unroll
                for (int r4 = 0; r4 < 4; ++r4) e4[r4] = __expf(s[r4] * SCALE) * rinv[f];
                int row_l = w * 16 + q;                     // 0..127
                int c_l = (kc * 4 + g) ^ (row_l & 7);       // swizzled 16B chunk
                *(f32x4*)&Pf[row_l * 64 + c_l * 4] = e4;
                bf16x4 p4;
#pragma unroll
                for (int r4 = 0; r4 < 4; ++r4) p4[r4] = (__bf16)e4[r4];
                pk[f][kc] = __builtin_bit_cast(int2, p4);
            }
            WAIT_LGKM0(); BAR();
            // ---- fill-style store: full 128B lines per 8-lane group ----
#pragma unroll
            for (int i = 0; i < 4; ++i) {
                int idx = t + 512 * i;                      // 0..2047
                int row128 = idx >> 4, c16 = idx & 15;
                int pc = c16 ^ (row128 & 7);
                f32x4 v = *(const f32x4*)&Pf[row128 * 64 + pc * 4];
                int grow = q0 + (row128 >> 4) * 32 + f * 16 + (row128 & 15);
                float* dst = wout + ((size_t)bh * 2048 + grow) * 2048 + kt + c16 * 4;
                *(f32x4*)dst = v;
            }
            BAR();   // Pf reads done before next f-half overwrites
        }

        // ---- PV: build A-fragments via shuffles ----
        int src0 = q + ((lane & 16) << 1);
        int src1 = src0 + 16;
        bool hi = lane >= 32;
        __builtin_amdgcn_s_setprio(1);
#pragma unroll
        for (int f = 0; f < 2; ++f) {
#pragma unroll
            for (int ks = 0; ks < 2; ++ks) {
                int2 A0 = pk[f][2 * ks], A1 = pk[f][2 * ks + 1];
                int l0a = __shfl(A0.x, src0), l0b = __shfl(A1.x, src0);
                int l1a = __shfl(A0.y, src0), l1b = __shfl(A1.y, src0);
                int h0a = __shfl(A0.x, src1), h0b = __shfl(A1.x, src1);
                int h1a = __shfl(A0.y, src1), h1b = __shfl(A1.y, src1);
                int4 ai;
                ai.x = hi ? l0b : l0a;
                ai.y = hi ? l1b : l1a;
                ai.z = hi ? h0b : h0a;
                ai.w = hi ? h1b : h1a;
                bf16x8 ap = __builtin_bit_cast(bf16x8, ai);
#pragma unroll
                for (int dc = 0; dc < 4; ++dc) {
                    int vrow = dc * 16 + q;
                    bf16x8 bv = *(const bf16x8*)((const char*)Vc + vrow * 128 + ((ks * 64 + g * 16) ^ ((vrow & 7) << 4)));
                    cacc[f][dc] = __builtin_amdgcn_mfma_f32_16x16x32_bf16(ap, bv, cacc[f][dc], 0, 0, 0);
                }
            }
        }
        __builtin_amdgcn_s_setprio(0);
        WAIT_LGKM0();
        if (nx) { WAIT_VM8(); BAR(); }   // retire the 2 K/V gloads; 8 weight stores stay in flight
        cur ^= 1;
    }

    // epilogue: ctx merged; PV D-layout: q-row = g*4+r4 (per tile), d = lane&15
    int bb = bh >> 4, h = bh & 15;
#pragma unroll
    for (int f = 0; f < 2; ++f)
#pragma unroll
        for (int dc = 0; dc < 4; ++dc)
#pragma unroll
            for (int r4 = 0; r4 < 4; ++r4) {
                int qg = q0 + w * 32 + f * 16 + (g << 2) + r4;
                int d = dc * 16 + q;
                ctx[((size_t)bb * 2048 + qg) * 1024 + h * 64 + d] = (__bf16)cacc[f][dc][r4];
            }
}

extern "C" void kernel_launch(void* const* d_in, const int* in_sizes, int n_in,
                              void* d_out, int out_size, void* d_ws, size_t ws_size,
                              hipStream_t stream) {
    const float* q  = (const float*)d_in[0];
    const float* k  = (const float*)d_in[1];
    const float* v  = (const float*)d_in[2];
    const float* Wq = (const float*)d_in[3];
    const float* bq = (const float*)d_in[4];
    const float* Wk = (const float*)d_in[5];
    const float* bk = (const float*)d_in[6];
    const float* Wv = (const float*)d_in[7];
    const float* bv = (const float*)d_in[8];
    const float* Wo = (const float*)d_in[9];
    const float* bo = (const float*)d_in[10];
    __bf16* ws = (__bf16*)d_ws;
    float* out  = (float*)d_out;          // [8192][1024] fp32
    float* wout = out + 8388608;          // weights [4][16][2048][2048] fp32
    float* rsum = (float*)d_ws;           // reuse XQ region after gemm<0> (512KB)

    convert_k<<<dim3(14336), dim3(256), 0, stream>>>(q, k, v, Wq, Wk, Wv, Wo, ws);
    gemm_k<0><<<dim3(64, 8, 3), dim3(256), 0, stream>>>(ws, bq, bk, bv, bo, out);
    rowsum_k<<<dim3(8, 64), dim3(512), 0, stream>>>(ws, rsum);
    attnw_k<<<dim3(8, 64), dim3(512), 0, stream>>>(ws, rsum, ws, wout);
    gemm_k<1><<<dim3(64, 8, 1), dim3(256), 0, stream>>>(ws, bq, bk, bv, bo, out);
}

// Round 21
// 492.763 us; speedup vs baseline: 1.0054x; 1.0054x over previous
//
#include <hip/hip_runtime.h>
#include <hip/hip_bf16.h>

typedef __bf16 bf16x8 __attribute__((ext_vector_type(8)));
typedef __bf16 bf16x4 __attribute__((ext_vector_type(4)));
typedef float f32x4 __attribute__((ext_vector_type(4)));

// ---- problem constants: B=4, S=2048, E=1024, H=16, D=64 ----
// ws layout (bf16 element offsets)
constexpr size_t XQ_OFF = 0;                 // x bf16 [8192][1024] x3 ; reused as f32 rowsums after gemm0
constexpr size_t WQ_OFF = 25165824;          // W bf16 [1024][1024] x4
constexpr size_t Q_OFF  = 29360128;          // Q bf16 [bh][s][d]
constexpr size_t KK_OFF = 37748736;          // K bf16 [bh][s][d]
constexpr size_t VT_OFF = 46137344;          // V^T bf16 [bh][d][s]
constexpr size_t CTX_OFF= 54525952;          // ctx merged bf16 [8192][1024]

__device__ __forceinline__ void gload16(const void* g, void* s) {
    __builtin_amdgcn_global_load_lds((__attribute__((address_space(1))) void*)g,
                                     (__attribute__((address_space(3))) void*)s, 16, 0, 0);
}
#define WAIT_VM0()   asm volatile("s_waitcnt vmcnt(0)" ::: "memory")
#define WAIT_VM4()   asm volatile("s_waitcnt vmcnt(4)" ::: "memory")
#define WAIT_VM8()   asm volatile("s_waitcnt vmcnt(8)" ::: "memory")
#define WAIT_LGKM0() asm volatile("s_waitcnt lgkmcnt(0)" ::: "memory")
#define BAR()        __builtin_amdgcn_s_barrier()

// ---------------- convert fp32 -> bf16 into ws ----------------
__global__ __launch_bounds__(256) void convert_k(
    const float* __restrict__ q, const float* __restrict__ k, const float* __restrict__ v,
    const float* __restrict__ Wq, const float* __restrict__ Wk, const float* __restrict__ Wv,
    const float* __restrict__ Wo, __bf16* __restrict__ ws) {
    int id = blockIdx.x * 256 + threadIdx.x;
    const int NX = 1048576;
    const int NW = 131072;
    const float* src; size_t dst; int local;
    if (id < 3 * NX) {
        int z = id / NX; local = id - z * NX;
        src = (z == 0) ? q : ((z == 1) ? k : v);
        dst = XQ_OFF + (size_t)z * 8388608;
    } else {
        int i2 = id - 3 * NX;
        int z = i2 / NW; local = i2 - z * NW;
        src = (z == 0) ? Wq : ((z == 1) ? Wk : ((z == 2) ? Wv : Wo));
        dst = WQ_OFF + (size_t)z * 1048576;
    }
    const float4* s4 = (const float4*)(src + (size_t)local * 8);
    float4 a = s4[0], b = s4[1];
    bf16x8 o;
    o[0]=(__bf16)a.x; o[1]=(__bf16)a.y; o[2]=(__bf16)a.z; o[3]=(__bf16)a.w;
    o[4]=(__bf16)b.x; o[5]=(__bf16)b.y; o[6]=(__bf16)b.z; o[7]=(__bf16)b.w;
    *(bf16x8*)(ws + dst + (size_t)local * 8) = o;
}

// ---------------- GEMM  C = A @ B^T (+bias), 128x128/BK32, 2-phase dbuf ----------------
template<int MODE>
__global__ __launch_bounds__(256) void gemm_k(
    __bf16* __restrict__ ws,
    const float* __restrict__ bq, const float* __restrict__ bk,
    const float* __restrict__ bv, const float* __restrict__ bo,
    float* __restrict__ out) {
    const int K = 1024;
    unsigned n = blockIdx.x + 64u * (blockIdx.y + 8u * blockIdx.z);
    unsigned cpx = (MODE == 0) ? 192u : 64u;
    unsigned m_ = (n & 7u) * cpx + (n >> 3);
    unsigned bx = m_ & 63u;
    unsigned rest = m_ >> 6;
    unsigned by = rest & 7u;
    unsigned bz = rest >> 3;

    int z = (int)bz;
    const __bf16* A; const __bf16* Bm; const float* bias;
    if (MODE == 0) {
        A    = ws + XQ_OFF + (size_t)z * 8388608;
        Bm   = ws + WQ_OFF + (size_t)z * 1048576;
        bias = (z == 0) ? bq : ((z == 1) ? bk : bv);
    } else {
        A    = ws + CTX_OFF;
        Bm   = ws + WQ_OFF + (size_t)3 * 1048576;
        bias = bo;
    }
    int row0 = (int)bx * 128, col0 = (int)by * 128;
    __shared__ __align__(16) __bf16 As[2][128 * 32];
    __shared__ __align__(16) __bf16 Bs[2][128 * 32];
    int t = threadIdx.x, lane = t & 63, w = t >> 6;
    int wr = w >> 1, wc = w & 1;
    f32x4 acc[4][4];
#pragma unroll
    for (int i = 0; i < 4; ++i)
#pragma unroll
        for (int j = 0; j < 4; ++j) acc[i][j] = (f32x4){0.f, 0.f, 0.f, 0.f};

    auto stage = [&](int buf, int kt) {
#pragma unroll
        for (int i = 0; i < 2; ++i) {
            int e = ((i * 4 + w) * 64 + lane) * 8;
            int r = e >> 5, c = e & 31;
            gload16(A  + (size_t)(row0 + r) * K + kt + c, &As[buf][e]);
            gload16(Bm + (size_t)(col0 + r) * K + kt + c, &Bs[buf][e]);
        }
    };

    stage(0, 0);
    int cur = 0;
    for (int kt = 0; kt < K; kt += 32) {
        bool nx = kt + 32 < K;
        if (nx) { stage(cur ^ 1, kt + 32); WAIT_VM4(); }
        else    { WAIT_VM0(); }
        BAR();
        const __bf16* Ac = As[cur];
        const __bf16* Bc = Bs[cur];
        bf16x8 af[4], bfr[4];
#pragma unroll
        for (int f = 0; f < 4; ++f) {
            af[f]  = *(const bf16x8*)&Ac[(wr * 64 + f * 16 + (lane & 15)) * 32 + (lane >> 4) * 8];
            bfr[f] = *(const bf16x8*)&Bc[(wc * 64 + f * 16 + (lane & 15)) * 32 + (lane >> 4) * 8];
        }
#pragma unroll
        for (int fr = 0; fr < 4; ++fr)
#pragma unroll
            for (int fc = 0; fc < 4; ++fc)
                acc[fr][fc] = __builtin_amdgcn_mfma_f32_16x16x32_bf16(af[fr], bfr[fc], acc[fr][fc], 0, 0, 0);
        WAIT_LGKM0();
        BAR();
        cur ^= 1;
    }

    if (MODE == 0) {
        __bf16* dqk = ws + Q_OFF + (size_t)z * 8388608;
        __bf16* dvt = ws + VT_OFF;
#pragma unroll
        for (int fr = 0; fr < 4; ++fr)
#pragma unroll
            for (int fc = 0; fc < 4; ++fc)
#pragma unroll
                for (int r = 0; r < 4; ++r) {
                    int m = row0 + wr * 64 + fr * 16 + ((lane >> 4) << 2) + r;
                    int nn = col0 + wc * 64 + fc * 16 + (lane & 15);
                    float val = acc[fr][fc][r] + bias[nn];
                    int bb = m >> 11, s = m & 2047, h = nn >> 6, d = nn & 63;
                    size_t bh = (size_t)bb * 16 + h;
                    if (z < 2) dqk[bh * 131072 + (size_t)s * 64 + d] = (__bf16)val;
                    else       dvt[bh * 131072 + (size_t)d * 2048 + s] = (__bf16)val;
                }
    } else {
#pragma unroll
        for (int fr = 0; fr < 4; ++fr)
#pragma unroll
            for (int fc = 0; fc < 4; ++fc)
#pragma unroll
                for (int r = 0; r < 4; ++r) {
                    int m = row0 + wr * 64 + fr * 16 + ((lane >> 4) << 2) + r;
                    int nn = col0 + wc * 64 + fc * 16 + (lane & 15);
                    out[(size_t)m * 1024 + nn] = acc[fr][fc][r] + bias[nn];
                }
    }
}

// ---------------- pass 1: rowsums of exp(QK^T/8), QBLK=256, Q in regs ----------------
__global__ __launch_bounds__(512) void rowsum_k(const __bf16* __restrict__ ws,
                                                float* __restrict__ rs_out) {
    unsigned n = blockIdx.x + 8u * blockIdx.y;
    unsigned m = (n & 7u) * 64u + (n >> 3);
    int bh = (int)(m >> 3);
    int q0 = (int)(m & 7u) * 256;
    const __bf16* Qb = ws + Q_OFF  + (size_t)bh * 131072;
    const __bf16* Kb = ws + KK_OFF + (size_t)bh * 131072;
    __shared__ __align__(16) __bf16 Ks[2][64 * 64];
    int t = threadIdx.x, lane = t & 63, w = t >> 6, g = lane >> 4;
    const float SCALE = 0.125f;

    bf16x8 aq[2][2];
#pragma unroll
    for (int f = 0; f < 2; ++f) {
        int qr = q0 + w * 32 + f * 16 + (lane & 15);
        aq[f][0] = *(const bf16x8*)&Qb[(size_t)qr * 64 + g * 8];
        aq[f][1] = *(const bf16x8*)&Qb[(size_t)qr * 64 + 32 + g * 8];
    }

    { int r = t >> 3, c8 = t & 7;
      gload16(Kb + (size_t)r * 64 + ((c8 ^ (r & 7)) << 3), &Ks[0][t * 8]); }
    WAIT_VM0(); BAR();

    float rs[8] = {0.f,0.f,0.f,0.f,0.f,0.f,0.f,0.f};
    int cur = 0;
    for (int kt = 0; kt < 2048; kt += 64) {
        bool nx = kt < 1984;
        if (nx) {
            int r = t >> 3, c8 = t & 7;
            gload16(Kb + (size_t)(kt + 64 + r) * 64 + ((c8 ^ (r & 7)) << 3), &Ks[cur ^ 1][t * 8]);
        }
        const __bf16* Kc = Ks[cur];
        __builtin_amdgcn_s_setprio(1);
#pragma unroll
        for (int kc = 0; kc < 4; ++kc) {
            int krow = kc * 16 + (lane & 15);
            bf16x8 b0 = *(const bf16x8*)((const char*)Kc + krow * 128 + ((g * 16) ^ ((krow & 7) << 4)));
            bf16x8 b1 = *(const bf16x8*)((const char*)Kc + krow * 128 + (((4 + g) * 16) ^ ((krow & 7) << 4)));
#pragma unroll
            for (int f = 0; f < 2; ++f) {
                f32x4 s = (f32x4){0.f, 0.f, 0.f, 0.f};
                s = __builtin_amdgcn_mfma_f32_16x16x32_bf16(aq[f][0], b0, s, 0, 0, 0);
                s = __builtin_amdgcn_mfma_f32_16x16x32_bf16(aq[f][1], b1, s, 0, 0, 0);
#pragma unroll
                for (int r4 = 0; r4 < 4; ++r4) rs[f * 4 + r4] += __expf(s[r4] * SCALE);
            }
        }
        __builtin_amdgcn_s_setprio(0);
        WAIT_LGKM0();
        if (nx) WAIT_VM0();
        BAR();
        cur ^= 1;
    }
#pragma unroll
    for (int msk = 1; msk < 16; msk <<= 1)
#pragma unroll
        for (int i = 0; i < 8; ++i) rs[i] += __shfl_xor(rs[i], msk);
    if ((lane & 15) == 0) {
#pragma unroll
        for (int f = 0; f < 2; ++f)
#pragma unroll
            for (int r4 = 0; r4 < 4; ++r4)
                rs_out[(size_t)bh * 2048 + q0 + w * 32 + f * 16 + g * 4 + r4] = rs[f * 4 + r4];
    }
}

// ---------------- pass 2: swapped QK^T; weights staged f32 in LDS, stored FULL-LINE ----------------
// Per f-half: compute -> Pf LDS (32KB, XOR-swizzled 16B chunks) -> fill-style store where
// lanes 0-15 write 16 consecutive 16B chunks of one row => each 8-lane group = one full 128B line.
__global__ __launch_bounds__(512) void attnw_k(const __bf16* __restrict__ ws,
                                               const float* __restrict__ rsf,
                                               __bf16* __restrict__ wsw,
                                               float* __restrict__ wout) {
    unsigned n = blockIdx.x + 8u * blockIdx.y;
    unsigned m = (n & 7u) * 64u + (n >> 3);
    int bh = (int)(m >> 3);
    int q0 = (int)(m & 7u) * 256;

    const __bf16* Qb = ws + Q_OFF  + (size_t)bh * 131072;
    const __bf16* Kb = ws + KK_OFF + (size_t)bh * 131072;
    const __bf16* Vb = ws + VT_OFF + (size_t)bh * 131072;
    __bf16* ctx = wsw + CTX_OFF;

    int t = threadIdx.x, lane = t & 63, w = t >> 6, g = lane >> 4, q = lane & 15;
    __shared__ __align__(16) __bf16 Ks[2][64 * 64];
    __shared__ __align__(16) __bf16 Vts[2][64 * 64];
    __shared__ __align__(16) float Pf[128 * 64];        // 32KB, one f-half at a time
    const float SCALE = 0.125f;

    bf16x8 aq[2][2];
#pragma unroll
    for (int f = 0; f < 2; ++f) {
        int qr = q0 + w * 32 + f * 16 + q;
        aq[f][0] = *(const bf16x8*)&Qb[(size_t)qr * 64 + g * 8];
        aq[f][1] = *(const bf16x8*)&Qb[(size_t)qr * 64 + 32 + g * 8];
    }
    float rinv[2];
#pragma unroll
    for (int f = 0; f < 2; ++f)
        rinv[f] = 1.f / rsf[(size_t)bh * 2048 + q0 + w * 32 + f * 16 + q];

    { int r = t >> 3, c8 = t & 7;
      gload16(Kb + (size_t)r * 64   + ((c8 ^ (r & 7)) << 3), &Ks[0][t * 8]);
      gload16(Vb + (size_t)r * 2048 + ((c8 ^ (r & 7)) << 3), &Vts[0][t * 8]); }
    WAIT_VM0(); BAR();

    f32x4 cacc[2][4];
#pragma unroll
    for (int f = 0; f < 2; ++f)
#pragma unroll
        for (int dc = 0; dc < 4; ++dc) cacc[f][dc] = (f32x4){0.f, 0.f, 0.f, 0.f};

    int cur = 0;
    for (int kt = 0; kt < 2048; kt += 64) {
        bool nx = kt < 1984;
        if (nx) {
            int r = t >> 3, c8 = t & 7;
            gload16(Kb + (size_t)(kt + 64 + r) * 64 + ((c8 ^ (r & 7)) << 3), &Ks[cur ^ 1][t * 8]);
            gload16(Vb + (size_t)r * 2048 + (kt + 64) + ((c8 ^ (r & 7)) << 3), &Vts[cur ^ 1][t * 8]);
        }
        const __bf16* Kc = Ks[cur];
        const __bf16* Vc = Vts[cur];

        int2 pk[2][4];
#pragma unroll
        for (int f = 0; f < 2; ++f) {
            // ---- QK^T (swapped) -> exp*rinv -> Pf LDS + bf16 pack ----
#pragma unroll
            for (int kc = 0; kc < 4; ++kc) {
                int krow = kc * 16 + q;
                bf16x8 b0 = *(const bf16x8*)((const char*)Kc + krow * 128 + ((g * 16) ^ ((krow & 7) << 4)));
                bf16x8 b1 = *(const bf16x8*)((const char*)Kc + krow * 128 + (((4 + g) * 16) ^ ((krow & 7) << 4)));
                f32x4 s = (f32x4){0.f, 0.f, 0.f, 0.f};
                s = __builtin_amdgcn_mfma_f32_16x16x32_bf16(b0, aq[f][0], s, 0, 0, 0);  // A=K, B=Q
                s = __builtin_amdgcn_mfma_f32_16x16x32_bf16(b1, aq[f][1], s, 0, 0, 0);
                f32x4 e4;
#pragma unroll
                for (int r4 = 0; r4 < 4; ++r4) e4[r4] = __expf(s[r4] * SCALE) * rinv[f];
                int row_l = w * 16 + q;                     // 0..127
                int c_l = (kc * 4 + g) ^ (row_l & 7);       // swizzled 16B chunk
                *(f32x4*)&Pf[row_l * 64 + c_l * 4] = e4;
                bf16x4 p4;
#pragma unroll
                for (int r4 = 0; r4 < 4; ++r4) p4[r4] = (__bf16)e4[r4];
                pk[f][kc] = __builtin_bit_cast(int2, p4);
            }
            WAIT_LGKM0(); BAR();
            // ---- fill-style store: full 128B lines per 8-lane group ----
#pragma unroll
            for (int i = 0; i < 4; ++i) {
                int idx = t + 512 * i;                      // 0..2047
                int row128 = idx >> 4, c16 = idx & 15;
                int pc = c16 ^ (row128 & 7);
                f32x4 v = *(const f32x4*)&Pf[row128 * 64 + pc * 4];
                int grow = q0 + (row128 >> 4) * 32 + f * 16 + (row128 & 15);
                float* dst = wout + ((size_t)bh * 2048 + grow) * 2048 + kt + c16 * 4;
                *(f32x4*)dst = v;
            }
            BAR();   // Pf reads done before next f-half overwrites
        }

        // ---- PV: build A-fragments via shuffles ----
        int src0 = q + ((lane & 16) << 1);
        int src1 = src0 + 16;
        bool hi = lane >= 32;
        __builtin_amdgcn_s_setprio(1);
#pragma unroll
        for (int f = 0; f < 2; ++f) {
#pragma unroll
            for (int ks = 0; ks < 2; ++ks) {
                int2 A0 = pk[f][2 * ks], A1 = pk[f][2 * ks + 1];
                int l0a = __shfl(A0.x, src0), l0b = __shfl(A1.x, src0);
                int l1a = __shfl(A0.y, src0), l1b = __shfl(A1.y, src0);
                int h0a = __shfl(A0.x, src1), h0b = __shfl(A1.x, src1);
                int h1a = __shfl(A0.y, src1), h1b = __shfl(A1.y, src1);
                int4 ai;
                ai.x = hi ? l0b : l0a;
                ai.y = hi ? l1b : l1a;
                ai.z = hi ? h0b : h0a;
                ai.w = hi ? h1b : h1a;
                bf16x8 ap = __builtin_bit_cast(bf16x8, ai);
#pragma unroll
                for (int dc = 0; dc < 4; ++dc) {
                    int vrow = dc * 16 + q;
                    bf16x8 bv = *(const bf16x8*)((const char*)Vc + vrow * 128 + ((ks * 64 + g * 16) ^ ((vrow & 7) << 4)));
                    cacc[f][dc] = __builtin_amdgcn_mfma_f32_16x16x32_bf16(ap, bv, cacc[f][dc], 0, 0, 0);
                }
            }
        }
        __builtin_amdgcn_s_setprio(0);
        WAIT_LGKM0();
        if (nx) { WAIT_VM8(); BAR(); }   // retire the 2 K/V gloads; 8 weight stores stay in flight
        cur ^= 1;
    }

    // epilogue: ctx merged; PV D-layout: q-row = g*4+r4 (per tile), d = lane&15
    int bb = bh >> 4, h = bh & 15;
#pragma unroll
    for (int f = 0; f < 2; ++f)
#pragma unroll
        for (int dc = 0; dc < 4; ++dc)
#pragma unroll
            for (int r4 = 0; r4 < 4; ++r4) {
                int qg = q0 + w * 32 + f * 16 + (g << 2) + r4;
                int d = dc * 16 + q;
                ctx[((size_t)bb * 2048 + qg) * 1024 + h * 64 + d] = (__bf16)cacc[f][dc][r4];
            }
}

extern "C" void kernel_launch(void* const* d_in, const int* in_sizes, int n_in,
                              void* d_out, int out_size, void* d_ws, size_t ws_size,
                              hipStream_t stream) {
    const float* q  = (const float*)d_in[0];
    const float* k  = (const float*)d_in[1];
    const float* v  = (const float*)d_in[2];
    const float* Wq = (const float*)d_in[3];
    const float* bq = (const float*)d_in[4];
    const float* Wk = (const float*)d_in[5];
    const float* bk = (const float*)d_in[6];
    const float* Wv = (const float*)d_in[7];
    const float* bv = (const float*)d_in[8];
    const float* Wo = (const float*)d_in[9];
    const float* bo = (const float*)d_in[10];
    __bf16* ws = (__bf16*)d_ws;
    float* out  = (float*)d_out;          // [8192][1024] fp32
    float* wout = out + 8388608;          // weights [4][16][2048][2048] fp32
    float* rsum = (float*)d_ws;           // reuse XQ region after gemm<0> (512KB)

    convert_k<<<dim3(14336), dim3(256), 0, stream>>>(q, k, v, Wq, Wk, Wv, Wo, ws);
    gemm_k<0><<<dim3(64, 8, 3), dim3(256), 0, stream>>>(ws, bq, bk, bv, bo, out);
    rowsum_k<<<dim3(8, 64), dim3(512), 0, stream>>>(ws, rsum);
    attnw_k<<<dim3(8, 64), dim3(512), 0, stream>>>(ws, rsum, ws, wout);
    gemm_k<1><<<dim3(64, 8, 1), dim3(256), 0, stream>>>(ws, bq, bk, bv, bo, out);
}